// Round 2
// baseline (660.612 us; speedup 1.0000x reference)
//
#include <hip/hip_runtime.h>
#include <stdint.h>

#define EMB 768
#define SEQ 2048
#define BATCH 4
#define NHEADS 12
#define HDIM 64
#define FFDIM 3072
#define NTOK (BATCH*SEQ)
#define LNEPS 1e-5f

typedef __attribute__((ext_vector_type(8))) short bf16x8;
typedef __attribute__((ext_vector_type(4))) float f32x4;

__device__ __forceinline__ uint16_t f2bf(float f){
  union { float f; uint32_t u; } v; v.f = f;
  uint32_t r = v.u + 0x7fffu + ((v.u >> 16) & 1u);
  return (uint16_t)(r >> 16);
}

// ---------- fp32 [K,N] -> bf16 [N,K] transposed weight conversion ----------
__global__ __launch_bounds__(256) void transpose_bf16(const float* __restrict__ w,
                                                      uint16_t* __restrict__ wt,
                                                      int K, int N){
  __shared__ uint16_t tile[32][33];
  int n0 = blockIdx.x*32, k0 = blockIdx.y*32;
  #pragma unroll
  for (int i=0;i<4;i++){
    int k = threadIdx.y + i*8;
    tile[k][threadIdx.x] = f2bf(w[(size_t)(k0+k)*N + n0 + threadIdx.x]);
  }
  __syncthreads();
  #pragma unroll
  for (int i=0;i<4;i++){
    int n = threadIdx.y + i*8;
    wt[(size_t)(n0+n)*K + k0 + threadIdx.x] = tile[threadIdx.x][n];
  }
}

// ---------- LayerNorm: fp32 in -> bf16 out, one wave per row ----------
__global__ __launch_bounds__(256) void ln_kernel(const float* __restrict__ x,
    const float* __restrict__ sc, const float* __restrict__ sh,
    uint16_t* __restrict__ out)
{
  int row = blockIdx.x*4 + (threadIdx.x>>6);
  int ln = threadIdx.x & 63;
  const float4* xr = (const float4*)(x + (size_t)row*EMB);
  float4 v0 = xr[ln], v1 = xr[64+ln], v2 = xr[128+ln];
  float s  = v0.x+v0.y+v0.z+v0.w + v1.x+v1.y+v1.z+v1.w + v2.x+v2.y+v2.z+v2.w;
  float s2 = v0.x*v0.x+v0.y*v0.y+v0.z*v0.z+v0.w*v0.w
           + v1.x*v1.x+v1.y*v1.y+v1.z*v1.z+v1.w*v1.w
           + v2.x*v2.x+v2.y*v2.y+v2.z*v2.z+v2.w*v2.w;
  #pragma unroll
  for (int off=1;off<64;off<<=1){ s += __shfl_xor(s,off); s2 += __shfl_xor(s2,off); }
  float mean = s*(1.f/768.f);
  float var  = s2*(1.f/768.f) - mean*mean;
  float rstd = rsqrtf(var + LNEPS);
  uint16_t* orow = out + (size_t)row*EMB;
  float4 vv[3] = {v0,v1,v2};
  #pragma unroll
  for (int i=0;i<3;i++){
    int c = (i*64+ln)*4;
    ushort4 o4;
    o4.x = f2bf((vv[i].x-mean)*rstd*sc[c+0] + sh[c+0]);
    o4.y = f2bf((vv[i].y-mean)*rstd*sc[c+1] + sh[c+1]);
    o4.z = f2bf((vv[i].z-mean)*rstd*sc[c+2] + sh[c+2]);
    o4.w = f2bf((vv[i].w-mean)*rstd*sc[c+3] + sh[c+3]);
    *(ushort4*)(orow + c) = o4;
  }
}

// ---------- GEMM: C[M,N] = A[M,K](bf16) * Bt[N,K](bf16)^T, tile 128x128x32 ----------
// MODE 0: store bf16          MODE 1: +bias +fp32 residual -> fp32
// MODE 2: +bias, gelu -> bf16 MODE 3: +bias +fp32 residual -> fp32 (final out)
template<int MODE>
__global__ __launch_bounds__(256) void gemm_bt(const uint16_t* __restrict__ A,
    const uint16_t* __restrict__ Bt0,
    const float* __restrict__ bias,
    const float* __restrict__ resid,
    void* __restrict__ outp,
    int N, int K, long bt_zstride, long out_zstride)
{
  __shared__ __align__(16) uint16_t As[128][32];
  __shared__ __align__(16) uint16_t Bs[128][32];
  const uint16_t* Bt = Bt0 + (size_t)blockIdx.z * bt_zstride;
  int tid = threadIdx.x;
  int wave = tid>>6, ln = tid&63, lane16 = ln&15, quad = ln>>4;
  int m0 = blockIdx.x*128, n0 = blockIdx.y*128;
  int wm = (wave>>1)*64, wn = (wave&1)*64;
  f32x4 zf = {0.f,0.f,0.f,0.f};
  f32x4 acc[4][4];
  #pragma unroll
  for (int i=0;i<4;i++)
    #pragma unroll
    for (int j=0;j<4;j++) acc[i][j]=zf;
  int ar = tid>>2;
  int ac = (tid&3)*8;
  const uint16_t* Arow0 = A  + (size_t)(m0+ar)*K    + ac;
  const uint16_t* Arow1 = A  + (size_t)(m0+ar+64)*K + ac;
  const uint16_t* Brow0 = Bt + (size_t)(n0+ar)*K    + ac;
  const uint16_t* Brow1 = Bt + (size_t)(n0+ar+64)*K + ac;
  for (int k0=0;k0<K;k0+=32){
    __syncthreads();
    *(uint4*)&As[ar][ac]    = *(const uint4*)(Arow0 + k0);
    *(uint4*)&As[ar+64][ac] = *(const uint4*)(Arow1 + k0);
    *(uint4*)&Bs[ar][ac]    = *(const uint4*)(Brow0 + k0);
    *(uint4*)&Bs[ar+64][ac] = *(const uint4*)(Brow1 + k0);
    __syncthreads();
    bf16x8 af[4], bfr[4];
    #pragma unroll
    for (int mi=0;mi<4;mi++) af[mi]  = *(const bf16x8*)&As[wm+mi*16+lane16][quad*8];
    #pragma unroll
    for (int ni=0;ni<4;ni++) bfr[ni] = *(const bf16x8*)&Bs[wn+ni*16+lane16][quad*8];
    #pragma unroll
    for (int mi=0;mi<4;mi++)
      #pragma unroll
      for (int ni=0;ni<4;ni++)
        acc[mi][ni] = __builtin_amdgcn_mfma_f32_16x16x32_bf16(af[mi], bfr[ni], acc[mi][ni], 0,0,0);
  }
  #pragma unroll
  for (int mi=0;mi<4;mi++){
    #pragma unroll
    for (int r=0;r<4;r++){
      int mrow = m0 + wm + mi*16 + quad*4 + r;
      #pragma unroll
      for (int ni=0;ni<4;ni++){
        int ncol = n0 + wn + ni*16 + lane16;
        float vv = acc[mi][ni][r];
        size_t idx = (size_t)mrow*N + ncol;
        if (MODE==0){
          ((uint16_t*)outp)[(size_t)blockIdx.z*out_zstride + idx] = f2bf(vv);
        } else if (MODE==1){
          ((float*)outp)[idx] = vv + bias[ncol] + resid[idx];
        } else if (MODE==2){
          float t = vv + bias[ncol];
          float g = 0.5f*t*(1.f + tanhf(0.7978845608028654f*(t + 0.044715f*t*t*t)));
          ((uint16_t*)outp)[idx] = f2bf(g);
        } else {
          // final output: fp32 (reference output dtype is float32)
          ((float*)outp)[idx] = vv + bias[ncol] + resid[idx];
        }
      }
    }
  }
}

// ---------- Flash attention: causal, 12 heads x 64 dim, online softmax ----------
// grid (SEQ/64, NHEADS, BATCH), block 256 (4 waves, 16 q-rows each)
__global__ __launch_bounds__(256) void attn_kernel(const uint16_t* __restrict__ q,
    const uint16_t* __restrict__ k, const uint16_t* __restrict__ v,
    uint16_t* __restrict__ ctx)
{
  __shared__ __align__(16) uint16_t Ks[32][64];
  __shared__ __align__(16) uint16_t Vs[32][64];
  __shared__ __align__(16) uint16_t Ps[4][16][32];
  int tid = threadIdx.x;
  int wave = tid>>6, ln = tid&63, lane16 = ln&15, quad = ln>>4;
  int b = blockIdx.z, h = blockIdx.y;
  int q0b = blockIdx.x*64;
  int q0w = q0b + wave*16;
  size_t base = ((size_t)b*SEQ)*EMB + (size_t)h*HDIM;
  bf16x8 qf[2];
  {
    size_t qoff = base + (size_t)(q0w + lane16)*EMB + quad*8;
    qf[0] = *(const bf16x8*)(q + qoff);
    qf[1] = *(const bf16x8*)(q + qoff + 32);
  }
  f32x4 zf = {0.f,0.f,0.f,0.f};
  f32x4 o[4]; o[0]=zf; o[1]=zf; o[2]=zf; o[3]=zf;
  float m_i[4] = {-3.0e38f,-3.0e38f,-3.0e38f,-3.0e38f};
  float l_i[4] = {0.f,0.f,0.f,0.f};
  int sr = tid>>3, scn = (tid&7)*8;
  const uint16_t* krow = k + base + (size_t)sr*EMB + scn;
  const uint16_t* vrow = v + base + (size_t)sr*EMB + scn;
  int kv_end = q0b + 64;
  for (int kv0=0; kv0<kv_end; kv0+=32){
    __syncthreads();
    *(uint4*)&Ks[sr][scn] = *(const uint4*)(krow + (size_t)kv0*EMB);
    *(uint4*)&Vs[sr][scn] = *(const uint4*)(vrow + (size_t)kv0*EMB);
    __syncthreads();
    f32x4 s0 = zf, s1 = zf;
    #pragma unroll
    for (int c=0;c<2;c++){
      bf16x8 kf0 = *(const bf16x8*)&Ks[lane16][c*32+quad*8];
      bf16x8 kf1 = *(const bf16x8*)&Ks[16+lane16][c*32+quad*8];
      s0 = __builtin_amdgcn_mfma_f32_16x16x32_bf16(qf[c], kf0, s0, 0,0,0);
      s1 = __builtin_amdgcn_mfma_f32_16x16x32_bf16(qf[c], kf1, s1, 0,0,0);
    }
    int ki0 = kv0 + lane16;
    #pragma unroll
    for (int r=0;r<4;r++){
      int qi = q0w + quad*4 + r;
      float a0 = (ki0      <= qi) ? s0[r]*0.125f : -1e30f;
      float a1 = (ki0 + 16 <= qi) ? s1[r]*0.125f : -1e30f;
      float rowmax = fmaxf(a0,a1);
      #pragma unroll
      for (int off=1;off<16;off<<=1) rowmax = fmaxf(rowmax, __shfl_xor(rowmax, off));
      float mn = fmaxf(m_i[r], rowmax);
      float alpha = __expf(m_i[r]-mn);
      float p0 = __expf(a0-mn);
      float p1 = __expf(a1-mn);
      float rs = p0+p1;
      #pragma unroll
      for (int off=1;off<16;off<<=1) rs += __shfl_xor(rs, off);
      l_i[r] = l_i[r]*alpha + rs;
      m_i[r] = mn;
      o[0][r]*=alpha; o[1][r]*=alpha; o[2][r]*=alpha; o[3][r]*=alpha;
      Ps[wave][quad*4+r][lane16]    = f2bf(p0);
      Ps[wave][quad*4+r][16+lane16] = f2bf(p1);
    }
    asm volatile("s_waitcnt lgkmcnt(0)" ::: "memory");
    bf16x8 pf = *(const bf16x8*)&Ps[wave][lane16][quad*8];
    #pragma unroll
    for (int t=0;t<4;t++){
      bf16x8 vf;
      #pragma unroll
      for (int j=0;j<8;j++) vf[j] = (short)Vs[quad*8+j][t*16+lane16];
      o[t] = __builtin_amdgcn_mfma_f32_16x16x32_bf16(pf, vf, o[t], 0,0,0);
    }
  }
  #pragma unroll
  for (int r=0;r<4;r++){
    float inv = 1.0f / l_i[r];
    size_t row = base + (size_t)(q0w + quad*4 + r)*EMB;
    #pragma unroll
    for (int t=0;t<4;t++)
      ctx[row + t*16 + lane16] = f2bf(o[t][r]*inv);
  }
}

extern "C" void kernel_launch(void* const* d_in, const int* in_sizes, int n_in,
                              void* d_out, int out_size, void* d_ws, size_t ws_size,
                              hipStream_t stream) {
  const float* x     = (const float*)d_in[0];
  const float* ln1_s = (const float*)d_in[1];
  const float* ln1_b = (const float*)d_in[2];
  const float* wq    = (const float*)d_in[3];
  const float* wk    = (const float*)d_in[4];
  const float* wv    = (const float*)d_in[5];
  const float* wo    = (const float*)d_in[6];
  const float* bo    = (const float*)d_in[7];
  const float* ln2_s = (const float*)d_in[8];
  const float* ln2_b = (const float*)d_in[9];
  const float* w1    = (const float*)d_in[10];
  const float* b1    = (const float*)d_in[11];
  const float* w2    = (const float*)d_in[12];
  const float* b2    = (const float*)d_in[13];

  // workspace layout (all offsets multiples of 256 B)
  uint16_t* wqkv_t = (uint16_t*)d_ws;                 // 3 x [768][768]
  uint16_t* wo_t   = wqkv_t + 3*EMB*EMB;              // [768][768]
  uint16_t* w1_t   = wo_t   + EMB*EMB;                // [3072][768]
  uint16_t* w2_t   = w1_t   + (size_t)FFDIM*EMB;      // [768][3072]
  uint16_t* xn     = w2_t   + (size_t)EMB*FFDIM;      // [8192][768] (reused as LN2 out)
  uint16_t* qkv    = xn     + (size_t)NTOK*EMB;       // 3 x [8192][768]
  uint16_t* ctx    = qkv    + (size_t)3*NTOK*EMB;     // [8192][768]
  uint16_t* hff    = qkv;                             // [8192][3072] overlays dead q/k/v/ctx
  float*    x1     = (float*)(ctx + (size_t)NTOK*EMB);// [8192][768] fp32

  dim3 tb(32,8);
  // weight convert + transpose -> bf16 [out,in]
  transpose_bf16<<<dim3(EMB/32,  EMB/32),  tb, 0, stream>>>(wq, wqkv_t,              EMB,   EMB);
  transpose_bf16<<<dim3(EMB/32,  EMB/32),  tb, 0, stream>>>(wk, wqkv_t + EMB*EMB,    EMB,   EMB);
  transpose_bf16<<<dim3(EMB/32,  EMB/32),  tb, 0, stream>>>(wv, wqkv_t + 2*EMB*EMB,  EMB,   EMB);
  transpose_bf16<<<dim3(EMB/32,  EMB/32),  tb, 0, stream>>>(wo, wo_t,                EMB,   EMB);
  transpose_bf16<<<dim3(FFDIM/32,EMB/32),  tb, 0, stream>>>(w1, w1_t,                EMB,   FFDIM);
  transpose_bf16<<<dim3(EMB/32,  FFDIM/32),tb, 0, stream>>>(w2, w2_t,                FFDIM, EMB);

  // LN1
  ln_kernel<<<NTOK/4, 256, 0, stream>>>(x, ln1_s, ln1_b, xn);
  // QKV (fused over z)
  gemm_bt<0><<<dim3(NTOK/128, EMB/128, 3), 256, 0, stream>>>(
      xn, wqkv_t, nullptr, nullptr, qkv, EMB, EMB,
      (long)EMB*EMB, (long)NTOK*EMB);
  // attention
  attn_kernel<<<dim3(SEQ/64, NHEADS, BATCH), 256, 0, stream>>>(
      qkv, qkv + (size_t)NTOK*EMB, qkv + (size_t)2*NTOK*EMB, ctx);
  // out-proj + bias + residual -> x1 (fp32)
  gemm_bt<1><<<dim3(NTOK/128, EMB/128, 1), 256, 0, stream>>>(
      ctx, wo_t, bo, x, x1, EMB, EMB, 0, 0);
  // LN2
  ln_kernel<<<NTOK/4, 256, 0, stream>>>(x1, ln2_s, ln2_b, xn);
  // FFN1 + gelu
  gemm_bt<2><<<dim3(NTOK/128, FFDIM/128, 1), 256, 0, stream>>>(
      xn, w1_t, b1, nullptr, hff, FFDIM, EMB, 0, 0);
  // FFN2 + bias + residual -> d_out (fp32)
  gemm_bt<3><<<dim3(NTOK/128, EMB/128, 1), 256, 0, stream>>>(
      hff, w2_t, b2, x1, d_out, EMB, FFDIM, 0, 0);
}

// Round 3
// 503.936 us; speedup vs baseline: 1.3109x; 1.3109x over previous
//
#include <hip/hip_runtime.h>
#include <stdint.h>

#define EMB 768
#define SEQ 2048
#define BATCH 4
#define NHEADS 12
#define HDIM 64
#define FFDIM 3072
#define NTOK (BATCH*SEQ)
#define LNEPS 1e-5f

typedef __attribute__((ext_vector_type(8))) short bf16x8;
typedef __attribute__((ext_vector_type(4))) float f32x4;

__device__ __forceinline__ uint16_t f2bf(float f){
  union { float f; uint32_t u; } v; v.f = f;
  uint32_t r = v.u + 0x7fffu + ((v.u >> 16) & 1u);
  return (uint16_t)(r >> 16);
}
__device__ __forceinline__ uint32_t pk2(float lo, float hi){
  return (uint32_t)f2bf(lo) | ((uint32_t)f2bf(hi) << 16);
}

// async global->LDS, 16B per lane. LDS dest = wave-uniform base + lane*16.
typedef __attribute__((address_space(3))) uint32_t lds32_t;
typedef __attribute__((address_space(1))) const uint32_t glb32_t;
__device__ __forceinline__ void gload16(const void* g, void* l){
  __builtin_amdgcn_global_load_lds((glb32_t*)(uintptr_t)g,
                                   (lds32_t*)(uintptr_t)l, 16, 0, 0);
}

// ---------- fp32 [K,N] -> bf16 [N,K] transposed weight conversion ----------
__global__ __launch_bounds__(256) void transpose_bf16(const float* __restrict__ w,
                                                      uint16_t* __restrict__ wt,
                                                      int K, int N){
  __shared__ uint16_t tile[32][33];
  int n0 = blockIdx.x*32, k0 = blockIdx.y*32;
  #pragma unroll
  for (int i=0;i<4;i++){
    int k = threadIdx.y + i*8;
    tile[k][threadIdx.x] = f2bf(w[(size_t)(k0+k)*N + n0 + threadIdx.x]);
  }
  __syncthreads();
  #pragma unroll
  for (int i=0;i<4;i++){
    int n = threadIdx.y + i*8;
    wt[(size_t)(n0+n)*K + k0 + threadIdx.x] = tile[threadIdx.x][n];
  }
}

// ---------- LayerNorm: fp32 in -> bf16 out, one wave per row ----------
__global__ __launch_bounds__(256) void ln_kernel(const float* __restrict__ x,
    const float* __restrict__ sc, const float* __restrict__ sh,
    uint16_t* __restrict__ out)
{
  int row = blockIdx.x*4 + (threadIdx.x>>6);
  int ln = threadIdx.x & 63;
  const float4* xr = (const float4*)(x + (size_t)row*EMB);
  float4 v0 = xr[ln], v1 = xr[64+ln], v2 = xr[128+ln];
  float s  = v0.x+v0.y+v0.z+v0.w + v1.x+v1.y+v1.z+v1.w + v2.x+v2.y+v2.z+v2.w;
  float s2 = v0.x*v0.x+v0.y*v0.y+v0.z*v0.z+v0.w*v0.w
           + v1.x*v1.x+v1.y*v1.y+v1.z*v1.z+v1.w*v1.w
           + v2.x*v2.x+v2.y*v2.y+v2.z*v2.z+v2.w*v2.w;
  #pragma unroll
  for (int off=1;off<64;off<<=1){ s += __shfl_xor(s,off); s2 += __shfl_xor(s2,off); }
  float mean = s*(1.f/768.f);
  float var  = s2*(1.f/768.f) - mean*mean;
  float rstd = rsqrtf(var + LNEPS);
  uint16_t* orow = out + (size_t)row*EMB;
  float4 vv[3] = {v0,v1,v2};
  #pragma unroll
  for (int i=0;i<3;i++){
    int c = (i*64+ln)*4;
    ushort4 o4;
    o4.x = f2bf((vv[i].x-mean)*rstd*sc[c+0] + sh[c+0]);
    o4.y = f2bf((vv[i].y-mean)*rstd*sc[c+1] + sh[c+1]);
    o4.z = f2bf((vv[i].z-mean)*rstd*sc[c+2] + sh[c+2]);
    o4.w = f2bf((vv[i].w-mean)*rstd*sc[c+3] + sh[c+3]);
    *(ushort4*)(orow + c) = o4;
  }
}

// ---------- GEMM: C[M,N] = A[M,K](bf16) * Bt[N,K](bf16)^T, tile 128x128x32 ----------
// MODE 0: store bf16 (z==2 -> V transposed [b][h][d][s])
// MODE 1: +bias +fp32 residual -> fp32
// MODE 2: +bias, gelu -> bf16
// MODE 3: +bias +fp32 residual -> fp32 (final out)
template<int MODE>
__global__ __launch_bounds__(256) void gemm_bt(const uint16_t* __restrict__ A,
    const uint16_t* __restrict__ Bt0,
    const float* __restrict__ bias,
    const float* __restrict__ resid,
    void* __restrict__ outp,
    uint16_t* __restrict__ vt_out,
    int N, int K, long bt_zstride, long out_zstride)
{
  __shared__ __align__(16) uint16_t As[128][32];
  __shared__ __align__(16) uint16_t Bs[128][32];
  const uint16_t* Bt = Bt0 + (size_t)blockIdx.z * bt_zstride;
  int tid = threadIdx.x;
  int wave = tid>>6, ln = tid&63, lane16 = ln&15, quad = ln>>4;
  int m0 = blockIdx.x*128, n0 = blockIdx.y*128;
  int wm = (wave>>1)*64, wn = (wave&1)*64;
  f32x4 zf = {0.f,0.f,0.f,0.f};
  f32x4 acc[4][4];
  #pragma unroll
  for (int i=0;i<4;i++)
    #pragma unroll
    for (int j=0;j<4;j++) acc[i][j]=zf;
  int ar = tid>>2;
  int ac = (tid&3)*8;
  const uint16_t* Arow0 = A  + (size_t)(m0+ar)*K    + ac;
  const uint16_t* Arow1 = A  + (size_t)(m0+ar+64)*K + ac;
  const uint16_t* Brow0 = Bt + (size_t)(n0+ar)*K    + ac;
  const uint16_t* Brow1 = Bt + (size_t)(n0+ar+64)*K + ac;
  // LDS layout is exactly tid*16B: As byte offset = ar*64 + ac*2 = tid*16
  char* lA = (char*)&As[0][0] + wave*1024;
  char* lB = (char*)&Bs[0][0] + wave*1024;
  for (int k0=0;k0<K;k0+=32){
    __syncthreads();
    gload16(Arow0 + k0, lA);
    gload16(Arow1 + k0, lA + 4096);
    gload16(Brow0 + k0, lB);
    gload16(Brow1 + k0, lB + 4096);
    __syncthreads();
    bf16x8 af[4], bfr[4];
    #pragma unroll
    for (int mi=0;mi<4;mi++) af[mi]  = *(const bf16x8*)&As[wm+mi*16+lane16][quad*8];
    #pragma unroll
    for (int ni=0;ni<4;ni++) bfr[ni] = *(const bf16x8*)&Bs[wn+ni*16+lane16][quad*8];
    #pragma unroll
    for (int mi=0;mi<4;mi++)
      #pragma unroll
      for (int ni=0;ni<4;ni++)
        acc[mi][ni] = __builtin_amdgcn_mfma_f32_16x16x32_bf16(af[mi], bfr[ni], acc[mi][ni], 0,0,0);
  }
  if (MODE==0 && blockIdx.z==2){
    // V: store transposed -> vt_out[b][h][d][s], pack 4 consecutive s per lane
    #pragma unroll
    for (int mi=0;mi<4;mi++){
      int mrow0 = m0 + wm + mi*16 + quad*4;
      int bb = mrow0 >> 11, s = mrow0 & 2047;
      #pragma unroll
      for (int ni=0;ni<4;ni++){
        int ncol = n0 + wn + ni*16 + lane16;
        int hh = ncol >> 6, dd = ncol & 63;
        ushort4 o4 = { f2bf(acc[mi][ni][0]), f2bf(acc[mi][ni][1]),
                       f2bf(acc[mi][ni][2]), f2bf(acc[mi][ni][3]) };
        *(ushort4*)(vt_out + ((size_t)((bb*NHEADS+hh)*HDIM + dd))*SEQ + s) = o4;
      }
    }
    return;
  }
  #pragma unroll
  for (int mi=0;mi<4;mi++){
    #pragma unroll
    for (int r=0;r<4;r++){
      int mrow = m0 + wm + mi*16 + quad*4 + r;
      #pragma unroll
      for (int ni=0;ni<4;ni++){
        int ncol = n0 + wn + ni*16 + lane16;
        float vv = acc[mi][ni][r];
        size_t idx = (size_t)mrow*N + ncol;
        if (MODE==0){
          ((uint16_t*)outp)[(size_t)blockIdx.z*out_zstride + idx] = f2bf(vv);
        } else if (MODE==1){
          ((float*)outp)[idx] = vv + bias[ncol] + resid[idx];
        } else if (MODE==2){
          float t = vv + bias[ncol];
          // gelu_tanh(t) = t * sigmoid(2c(t + 0.044715 t^3))
          float u = 1.5957691216057308f*(t + 0.044715f*t*t*t);
          ((uint16_t*)outp)[idx] = f2bf(t / (1.f + __expf(-u)));
        } else {
          ((float*)outp)[idx] = vv + bias[ncol] + resid[idx];
        }
      }
    }
  }
}

// ---------- Flash attention, S^T formulation ----------
// grid (SEQ/64, NHEADS, BATCH), block 256 (4 waves, 16 q-rows each)
// S^T = K*Q^T (C: row=kv, col=q) -> softmax reduce over regs + xor16/32
// P^T -> PV B-frag via 8 ds_bpermute; O^T = V^T * P^T, V^T staged from global vt.
__global__ __launch_bounds__(256) void attn_kernel(const uint16_t* __restrict__ q,
    const uint16_t* __restrict__ k, const uint16_t* __restrict__ vt,
    uint16_t* __restrict__ ctx)
{
  __shared__ __align__(16) uint16_t Ks[64][64];  // [kv][d], d-blocks XOR-swizzled
  __shared__ __align__(16) uint16_t Vs[64][64];  // [d][kv], kv-blocks XOR-swizzled
  const f32x4 zf = {0.f,0.f,0.f,0.f};
  int tid = threadIdx.x;
  int wave = tid>>6, ln = tid&63, l16 = ln&15, quad = ln>>4;
  int b = blockIdx.z, h = blockIdx.y;
  int q0 = blockIdx.x*64;
  int q0w = q0 + wave*16;
  // Q as B-fragment: n=q=l16, k=d=quad*8+j (+32 for second half)
  const uint16_t* qrow = q + ((size_t)(b*SEQ + q0w + l16))*EMB + h*HDIM + quad*8;
  bf16x8 qf0 = *(const bf16x8*)(qrow);
  bf16x8 qf1 = *(const bf16x8*)(qrow + 32);
  // staging: 4 threads per row, 2 swizzled 16B blocks each
  int srow = tid>>2;
  int sblk = (tid&3)*2;
  const uint16_t* kg = k  + ((size_t)(b*SEQ + srow))*EMB + h*HDIM + sblk*8;
  const uint16_t* vg = vt + ((size_t)((b*NHEADS + h)*HDIM + srow))*SEQ + sblk*8;
  uint16_t* ks0 = &Ks[srow][((sblk  ) ^ (srow&7))*8];
  uint16_t* ks1 = &Ks[srow][((sblk+1) ^ (srow&7))*8];
  uint16_t* vs0 = &Vs[srow][((sblk  ) ^ (srow&7))*8];
  uint16_t* vs1 = &Vs[srow][((sblk+1) ^ (srow&7))*8];
  f32x4 o0=zf, o1=zf, o2=zf, o3=zf;
  float m_l = -3.0e38f, l_l = 0.f;
  for (int kv0=0; kv0<=q0; kv0+=64){
    uint4 ka = *(const uint4*)(kg + (size_t)kv0*EMB);
    uint4 kb = *(const uint4*)(kg + (size_t)kv0*EMB + 8);
    uint4 va = *(const uint4*)(vg + kv0);
    uint4 vb = *(const uint4*)(vg + kv0 + 8);
    __syncthreads();
    *(uint4*)ks0 = ka; *(uint4*)ks1 = kb;
    *(uint4*)vs0 = va; *(uint4*)vs1 = vb;
    __syncthreads();
    #pragma unroll
    for (int cc=0; cc<2; cc++){
      int kvc = kv0 + cc*32;
      if (kvc > q0w + 15) break;              // wave-uniform causal skip
      bool have1 = (kvc + 16 <= q0w + 15);
      int r0 = cc*32 + l16;
      bf16x8 kf00 = *(const bf16x8*)&Ks[r0][((quad  ) ^ (r0&7))*8];
      bf16x8 kf01 = *(const bf16x8*)&Ks[r0][((quad+4) ^ (r0&7))*8];
      f32x4 st0 = __builtin_amdgcn_mfma_f32_16x16x32_bf16(kf00, qf0, zf, 0,0,0);
      st0 = __builtin_amdgcn_mfma_f32_16x16x32_bf16(kf01, qf1, st0, 0,0,0);
      f32x4 st1 = zf;
      if (have1){
        int r1 = r0 + 16;
        bf16x8 kf10 = *(const bf16x8*)&Ks[r1][((quad  ) ^ (r0&7))*8];
        bf16x8 kf11 = *(const bf16x8*)&Ks[r1][((quad+4) ^ (r0&7))*8];
        st1 = __builtin_amdgcn_mfma_f32_16x16x32_bf16(kf10, qf0, zf, 0,0,0);
        st1 = __builtin_amdgcn_mfma_f32_16x16x32_bf16(kf11, qf1, st1, 0,0,0);
      }
      int myq = q0w + l16;
      int kvq = kvc + 4*quad;
      bool mask0 = (kvc + 15 > q0w);
      bool mask1 = (kvc + 31 > q0w);
      float a0[4], a1[4];
      #pragma unroll
      for (int r=0;r<4;r++){
        a0[r] = (mask0 && (kvq + r > myq))              ? -1e30f : st0[r]*0.125f;
        a1[r] = (!have1 || (mask1 && (kvq+16+r > myq))) ? -1e30f : st1[r]*0.125f;
      }
      float cmax = fmaxf(fmaxf(fmaxf(a0[0],a0[1]),fmaxf(a0[2],a0[3])),
                         fmaxf(fmaxf(a1[0],a1[1]),fmaxf(a1[2],a1[3])));
      cmax = fmaxf(cmax, __shfl_xor(cmax,16));
      cmax = fmaxf(cmax, __shfl_xor(cmax,32));
      float mn = fmaxf(m_l, cmax);
      float alpha = __expf(m_l - mn);
      float p0[4], p1[4]; float rs = 0.f;
      #pragma unroll
      for (int r=0;r<4;r++){
        p0[r]=__expf(a0[r]-mn); p1[r]=__expf(a1[r]-mn); rs += p0[r]+p1[r];
      }
      rs += __shfl_xor(rs,16); rs += __shfl_xor(rs,32);
      l_l = l_l*alpha + rs; m_l = mn;
      #pragma unroll
      for (int r=0;r<4;r++){ o0[r]*=alpha; o1[r]*=alpha; o2[r]*=alpha; o3[r]*=alpha; }
      // P^T (C layout) -> PV B-fragment via shuffles
      uint32_t dwl[2] = { pk2(p0[0],p0[1]), pk2(p0[2],p0[3]) };
      uint32_t dwh[2] = { pk2(p1[0],p1[1]), pk2(p1[2],p1[3]) };
      union { uint32_t u[4]; bf16x8 v; } pb;
      #pragma unroll
      for (int bb=0;bb<4;bb++){
        int src = l16 + 16*((quad&1)*2 + (bb>>1));
        uint32_t lo = (uint32_t)__shfl((int)dwl[bb&1], src, 64);
        uint32_t hi = (uint32_t)__shfl((int)dwh[bb&1], src, 64);
        pb.u[bb] = (quad>>1) ? hi : lo;
      }
      int vb_ = ((cc*4+quad) ^ (l16&7))*8;
      bf16x8 vf0 = *(const bf16x8*)&Vs[ 0+l16][vb_];
      bf16x8 vf1 = *(const bf16x8*)&Vs[16+l16][vb_];
      bf16x8 vf2 = *(const bf16x8*)&Vs[32+l16][vb_];
      bf16x8 vf3 = *(const bf16x8*)&Vs[48+l16][vb_];
      o0 = __builtin_amdgcn_mfma_f32_16x16x32_bf16(vf0, pb.v, o0, 0,0,0);
      o1 = __builtin_amdgcn_mfma_f32_16x16x32_bf16(vf1, pb.v, o1, 0,0,0);
      o2 = __builtin_amdgcn_mfma_f32_16x16x32_bf16(vf2, pb.v, o2, 0,0,0);
      o3 = __builtin_amdgcn_mfma_f32_16x16x32_bf16(vf3, pb.v, o3, 0,0,0);
    }
  }
  float inv = 1.0f / l_l;
  uint16_t* crow = ctx + ((size_t)(b*SEQ + q0w + l16))*EMB + h*HDIM + quad*4;
  ushort4 w0 = { f2bf(o0[0]*inv), f2bf(o0[1]*inv), f2bf(o0[2]*inv), f2bf(o0[3]*inv) };
  ushort4 w1 = { f2bf(o1[0]*inv), f2bf(o1[1]*inv), f2bf(o1[2]*inv), f2bf(o1[3]*inv) };
  ushort4 w2 = { f2bf(o2[0]*inv), f2bf(o2[1]*inv), f2bf(o2[2]*inv), f2bf(o2[3]*inv) };
  ushort4 w3 = { f2bf(o3[0]*inv), f2bf(o3[1]*inv), f2bf(o3[2]*inv), f2bf(o3[3]*inv) };
  *(ushort4*)(crow     ) = w0;
  *(ushort4*)(crow + 16) = w1;
  *(ushort4*)(crow + 32) = w2;
  *(ushort4*)(crow + 48) = w3;
}

extern "C" void kernel_launch(void* const* d_in, const int* in_sizes, int n_in,
                              void* d_out, int out_size, void* d_ws, size_t ws_size,
                              hipStream_t stream) {
  const float* x     = (const float*)d_in[0];
  const float* ln1_s = (const float*)d_in[1];
  const float* ln1_b = (const float*)d_in[2];
  const float* wq    = (const float*)d_in[3];
  const float* wk    = (const float*)d_in[4];
  const float* wv    = (const float*)d_in[5];
  const float* wo    = (const float*)d_in[6];
  const float* bo    = (const float*)d_in[7];
  const float* ln2_s = (const float*)d_in[8];
  const float* ln2_b = (const float*)d_in[9];
  const float* w1    = (const float*)d_in[10];
  const float* b1    = (const float*)d_in[11];
  const float* w2    = (const float*)d_in[12];
  const float* b2    = (const float*)d_in[13];

  uint16_t* wqkv_t = (uint16_t*)d_ws;                 // 3 x [768][768]
  uint16_t* wo_t   = wqkv_t + 3*EMB*EMB;              // [768][768]
  uint16_t* w1_t   = wo_t   + EMB*EMB;                // [3072][768]
  uint16_t* w2_t   = w1_t   + (size_t)FFDIM*EMB;      // [768][3072]
  uint16_t* xn     = w2_t   + (size_t)EMB*FFDIM;      // [8192][768]
  uint16_t* qkv    = xn     + (size_t)NTOK*EMB;       // q,k normal; v slot unused
  uint16_t* ctx    = qkv    + (size_t)3*NTOK*EMB;     // [8192][768]
  uint16_t* hff    = qkv;                             // [8192][3072] overlays qkv+ctx
  float*    x1     = (float*)(ctx + (size_t)NTOK*EMB);// [8192][768] fp32
  uint16_t* vt     = (uint16_t*)(x1 + (size_t)NTOK*EMB); // [4][12][64][2048] V^T

  dim3 tb(32,8);
  transpose_bf16<<<dim3(EMB/32,  EMB/32),  tb, 0, stream>>>(wq, wqkv_t,              EMB,   EMB);
  transpose_bf16<<<dim3(EMB/32,  EMB/32),  tb, 0, stream>>>(wk, wqkv_t + EMB*EMB,    EMB,   EMB);
  transpose_bf16<<<dim3(EMB/32,  EMB/32),  tb, 0, stream>>>(wv, wqkv_t + 2*EMB*EMB,  EMB,   EMB);
  transpose_bf16<<<dim3(EMB/32,  EMB/32),  tb, 0, stream>>>(wo, wo_t,                EMB,   EMB);
  transpose_bf16<<<dim3(FFDIM/32,EMB/32),  tb, 0, stream>>>(w1, w1_t,                EMB,   FFDIM);
  transpose_bf16<<<dim3(EMB/32,  FFDIM/32),tb, 0, stream>>>(w2, w2_t,                FFDIM, EMB);

  ln_kernel<<<NTOK/4, 256, 0, stream>>>(x, ln1_s, ln1_b, xn);
  // QKV fused; z==2 (V) written transposed into vt
  gemm_bt<0><<<dim3(NTOK/128, EMB/128, 3), 256, 0, stream>>>(
      xn, wqkv_t, nullptr, nullptr, qkv, vt, EMB, EMB,
      (long)EMB*EMB, (long)NTOK*EMB);
  attn_kernel<<<dim3(SEQ/64, NHEADS, BATCH), 256, 0, stream>>>(
      qkv, qkv + (size_t)NTOK*EMB, vt, ctx);
  gemm_bt<1><<<dim3(NTOK/128, EMB/128, 1), 256, 0, stream>>>(
      ctx, wo_t, bo, x, x1, nullptr, EMB, EMB, 0, 0);
  ln_kernel<<<NTOK/4, 256, 0, stream>>>(x1, ln2_s, ln2_b, xn);
  gemm_bt<2><<<dim3(NTOK/128, FFDIM/128, 1), 256, 0, stream>>>(
      xn, w1_t, b1, nullptr, hff, nullptr, FFDIM, EMB, 0, 0);
  gemm_bt<3><<<dim3(NTOK/128, EMB/128, 1), 256, 0, stream>>>(
      hff, w2_t, b2, x1, d_out, nullptr, EMB, FFDIM, 0, 0);
}